// Round 16
// baseline (69.028 us; speedup 1.0000x reference)
//
#include <hip/hip_runtime.h>
#include <math.h>

#define EMBED 768
#define SEQ   2048
#define NB    8
// sqrt(768) * log2(e): scores are produced directly in log2 domain
#define QSCALE 39.98113776623437f

typedef short  short8 __attribute__((ext_vector_type(8)));
typedef float  f32x4  __attribute__((ext_vector_type(4)));
typedef float  f32x16 __attribute__((ext_vector_type(16)));
typedef unsigned int uint2v __attribute__((ext_vector_type(2)));

// ws layout, ushort element offsets
#define WHI_OFF  0u
#define WLO_OFF  147456u
#define QHI_OFF  294912u
#define QLO_OFF  (294912u + 1u*1048576u)
#define KHI_OFF  (294912u + 2u*1048576u)
#define KLO_OFF  (294912u + 3u*1048576u)
#define VT_OFF   (294912u + 4u*1048576u)
// bf16 partial region starts right after the ushort q/k/v region
#define OPU_OFF  5537792u                   // ushort offset of oP[8][16384][64] (bf16)
#define MPL_OFF  (5537792u + 8u*1048576u)   // ushort offset where f32 m/l begin

__device__ __forceinline__ ushort f2bf(float f) {          // round-to-nearest
    unsigned u = __float_as_uint(f);
    return (ushort)((u + 0x7FFFu + ((u >> 16) & 1u)) >> 16);
}
__device__ __forceinline__ ushort f2bf_trunc(float f) {    // cheap, for lo part
    return (ushort)(__float_as_uint(f) >> 16);
}
__device__ __forceinline__ float bf2f(ushort h) {
    return __uint_as_float(((unsigned)h) << 16);
}
__device__ __forceinline__ uint cvtpk(float a, float b) {  // [bf16(a) | bf16(b)<<16]
    uint r;
    asm("v_cvt_pk_bf16_f32 %0, %1, %2" : "=v"(r) : "v"(a), "v"(b));
    return r;
}
__device__ __forceinline__ float pklo(uint h) {            // low bf16 -> float
    return __uint_as_float(h << 16);
}
__device__ __forceinline__ float pkhi(uint h) {            // high bf16 -> float
    return __uint_as_float(h & 0xFFFF0000u);
}

union U8 { uint u[4]; short8 s; };

// ---------------------------------------------------------------------------
// Kernel 0: split W into bf16 hi/lo.  rows: [0,64)=Wq*QSCALE, [64,128)=Wk,
// [128,192)=Wv.
// ---------------------------------------------------------------------------
__global__ __launch_bounds__(256)
void split_w_kernel(const float* __restrict__ Wq, const float* __restrict__ Wk,
                    const float* __restrict__ Wv,
                    ushort* __restrict__ w_hi, ushort* __restrict__ w_lo)
{
    int idx = blockIdx.x * 256 + threadIdx.x;
    if (idx >= 192 * EMBED) return;
    int row = idx / EMBED, e = idx - row * EMBED;
    float f;
    if (row < 64)       f = Wq[row * EMBED + e] * QSCALE;
    else if (row < 128) f = Wk[(row - 64) * EMBED + e];
    else                f = Wv[(row - 128) * EMBED + e];
    ushort hi = f2bf(f);
    w_hi[idx] = hi;
    w_lo[idx] = f2bf_trunc(f - bf2f(hi));
}

// ---------------------------------------------------------------------------
// Kernel 1 (v8): QKV projection -- W via global_load_lds DMA (attn's proven
// [row][64] + XOR-swizzle tile pattern), x read DIRECTLY from global into
// registers and converted fp32->bf16 hi/lo in-register (cvt_pk) at fragment
// build time.  NO VALU ds_writes, NO lgkm drains, NO x LDS re-read.
// BM=64, 512 thr = 8 waves (wm x wn), grid 256, 2 waves/SIMD.
// LDS = 3 W-buffers x 40KB = 120KB; schedule = attn's 3-buffer 2-ahead with
// counted s_waitcnt vmcnt(13) (5 W-DMA + 8 x-loads per wave per chunk).
// 12 chunks (K=64), fully unrolled; x register sets keyed (c%3) and passed
// as explicit static macro args (fix for R15's ternary-on-array error).
// ---------------------------------------------------------------------------
__global__ __launch_bounds__(512)
void proj_kernel(const float* __restrict__ x,
                 const ushort* __restrict__ w_hi, const ushort* __restrict__ w_lo,
                 ushort* __restrict__ q_hi, ushort* __restrict__ q_lo,
                 ushort* __restrict__ k_hi, ushort* __restrict__ k_lo,
                 ushort* __restrict__ v_t)
{
    // per buffer: Whi [0, 12288) | Wlo [12288, 20480)   (ushort units, 40KB)
    __shared__ __align__(16) ushort wb[3][20480];

    const int t    = threadIdx.x;
    const int lane = t & 63;
    const int wid  = t >> 6;       // 0..7
    const int wm   = wid >> 2;     // 0,1: rows wm*32..+31
    const int wn   = wid & 3;      // 0..3: n-tiles {wn, 4+wn, 8+wn}
    const int ln   = lane & 15;
    const int kg   = lane >> 4;    // 0..3
    const int row0 = blockIdx.x * 64;

    const int srow8 = lane >> 3;                                // 0..7
    const int scol  = ((lane & 7) << 3) ^ ((lane >> 3) << 3);   // inverse swizzle

    // ---- W staging: 40 x 1KB DMA per chunk, 5 per wave ----
    auto stageW = [&](int c, int bf) {
        const int e0 = c * 64;
        ushort* base = &wb[bf][0];
#pragma unroll
        for (int s = 0; s < 5; ++s) {
            const int i = wid * 5 + s;          // 0..39
            if (i < 24) {                       // W hi: rows i*8..+7 of 192
                const int row = i * 8 + srow8;
                const ushort* gp = w_hi + (size_t)row * EMBED + e0 + scol;
                __builtin_amdgcn_global_load_lds(
                    (const __attribute__((address_space(1))) void*)gp,
                    (__attribute__((address_space(3))) void*)(base + i * 512),
                    16, 0, 0);
            } else {                            // W lo: rows (i-24)*8..+7 of 128
                const int il = i - 24;
                const int row = il * 8 + srow8;
                const ushort* gp = w_lo + (size_t)row * EMBED + e0 + scol;
                __builtin_amdgcn_global_load_lds(
                    (const __attribute__((address_space(1))) void*)gp,
                    (__attribute__((address_space(3))) void*)(base + 12288 + il * 512),
                    16, 0, 0);
            }
        }
    };

    // ---- x loads: 8 float4 per thread per chunk, straight to registers ----
#define XLOAD(e0, R) do {                                                        \
        const float* xp_ = x + (size_t)(row0 + wm * 32 + ln) * EMBED + (e0) + kg * 8; \
        R[0] = *(const float4*)xp_;                                              \
        R[1] = *(const float4*)(xp_ + 4);                                        \
        R[2] = *(const float4*)(xp_ + 32);                                       \
        R[3] = *(const float4*)(xp_ + 36);                                       \
        R[4] = *(const float4*)(xp_ + 16 * EMBED);                               \
        R[5] = *(const float4*)(xp_ + 16 * EMBED + 4);                           \
        R[6] = *(const float4*)(xp_ + 16 * EMBED + 32);                          \
        R[7] = *(const float4*)(xp_ + 16 * EMBED + 36);                          \
    } while (0)

    const f32x4 vzero = {0.f, 0.f, 0.f, 0.f};
    f32x4 acc[2][3];
#pragma unroll
    for (int mt = 0; mt < 2; ++mt)
#pragma unroll
        for (int j = 0; j < 3; ++j) acc[mt][j] = vzero;

#define COMPUTE(BF, R) do {                                                       \
        const ushort* WHB_ = &wb[BF][0];                                          \
        const ushort* WLB_ = &wb[BF][12288];                                      \
        U8 ah_[2][2], al_[2][2];                                                  \
        _Pragma("unroll")                                                         \
        for (int mt_ = 0; mt_ < 2; ++mt_)                                         \
            _Pragma("unroll")                                                     \
            for (int ks_ = 0; ks_ < 2; ++ks_) {                                   \
                float4 a_ = R[mt_ * 4 + ks_ * 2];                                 \
                float4 b_ = R[mt_ * 4 + ks_ * 2 + 1];                             \
                U8 H_, L_;                                                        \
                H_.u[0] = cvtpk(a_.x, a_.y);  H_.u[1] = cvtpk(a_.z, a_.w);        \
                H_.u[2] = cvtpk(b_.x, b_.y);  H_.u[3] = cvtpk(b_.z, b_.w);        \
                L_.u[0] = cvtpk(a_.x - pklo(H_.u[0]), a_.y - pkhi(H_.u[0]));      \
                L_.u[1] = cvtpk(a_.z - pklo(H_.u[1]), a_.w - pkhi(H_.u[1]));      \
                L_.u[2] = cvtpk(b_.x - pklo(H_.u[2]), b_.y - pkhi(H_.u[2]));      \
                L_.u[3] = cvtpk(b_.z - pklo(H_.u[3]), b_.w - pkhi(H_.u[3]));      \
                ah_[mt_][ks_] = H_;  al_[mt_][ks_] = L_;                          \
            }                                                                     \
        __builtin_amdgcn_s_setprio(1);                                            \
        _Pragma("unroll")                                                         \
        for (int j_ = 0; j_ < 3; ++j_) {                                          \
            const int ntg_ = j_ * 4 + wn;                                         \
            _Pragma("unroll")                                                     \
            for (int ks_ = 0; ks_ < 2; ++ks_) {                                   \
                const int rw_  = ntg_ * 16 + ln;                                  \
                const int off_ = rw_ * 64 + ((ks_ * 32 + kg * 8) ^ ((rw_ & 7) << 3)); \
                short8 bh_ = *(const short8*)(WHB_ + off_);                       \
                _Pragma("unroll")                                                 \
                for (int mt_ = 0; mt_ < 2; ++mt_)                                 \
                    acc[mt_][j_] = __builtin_amdgcn_mfma_f32_16x16x32_bf16(ah_[mt_][ks_].s, bh_, acc[mt_][j_], 0, 0, 0); \
                if (j_ < 2) {                                                     \
                    short8 bl_ = *(const short8*)(WLB_ + off_);                   \
                    _Pragma("unroll")                                             \
                    for (int mt_ = 0; mt_ < 2; ++mt_) {                           \
                        acc[mt_][j_] = __builtin_amdgcn_mfma_f32_16x16x32_bf16(ah_[mt_][ks_].s, bl_, acc[mt_][j_], 0, 0, 0); \
                        acc[mt_][j_] = __builtin_amdgcn_mfma_f32_16x16x32_bf16(al_[mt_][ks_].s, bh_, acc[mt_][j_], 0, 0, 0); \
                    }                                                             \
                }                                                                 \
            }                                                                     \
        }                                                                         \
        __builtin_amdgcn_s_setprio(0);                                            \
    } while (0)

    float4 xr0[8], xr1[8], xr2[8];      // 3 named register sets (c % 3)

    // prologue: chunks 0 and 1 in flight
    stageW(0, 0); XLOAD(0,  xr0);
    stageW(1, 1); XLOAD(64, xr1);

    // iter c: wait oldest chunk (counted), barrier, issue c+2 (into RNEXT,
    // the (c+2)%3 set -- static per instantiation), compute c from RSET.
#define ITER(C_, VMC, RSET, RNEXT) do {                                           \
        asm volatile("s_waitcnt vmcnt(" #VMC ")" ::: "memory");                   \
        __builtin_amdgcn_s_barrier();                                             \
        if ((C_) + 2 < 12) {                                                      \
            stageW((C_) + 2, ((C_) + 2) % 3);                                     \
            XLOAD(((C_) + 2) * 64, RNEXT);                                        \
        }                                                                         \
        COMPUTE((C_) % 3, RSET);                                                  \
    } while (0)

    ITER(0,  13, xr0, xr2);
    ITER(1,  13, xr1, xr0);
    ITER(2,  13, xr2, xr1);
    ITER(3,  13, xr0, xr2);
    ITER(4,  13, xr1, xr0);
    ITER(5,  13, xr2, xr1);
    ITER(6,  13, xr0, xr2);
    ITER(7,  13, xr1, xr0);
    ITER(8,  13, xr2, xr1);
    ITER(9,  13, xr0, xr2);
    ITER(10, 13, xr1, xr0);
    ITER(11,  0, xr2, xr0);
#undef ITER
#undef XLOAD
#undef COMPUTE

    // ---- epilogue: C layout col=lane&15, row=(lane>>4)*4+reg ----
#pragma unroll
    for (int mt = 0; mt < 2; ++mt) {
        const int rbase = row0 + wm * 32 + mt * 16 + kg * 4;
#pragma unroll
        for (int j = 0; j < 3; ++j) {
            const int col = (j * 4 + wn) * 16 + ln;
#pragma unroll
            for (int r = 0; r < 4; ++r) {
                int rg = rbase + r;
                int b = rg >> 11, s = rg & 2047;
                size_t rowoff = ((size_t)b * SEQ + s) * 64;
                float val = acc[mt][j][r];
                if (col < 64) {
                    ushort h = f2bf(val);
                    q_hi[rowoff + col] = h;
                    q_lo[rowoff + col] = f2bf_trunc(val - bf2f(h));
                } else if (col < 128) {
                    ushort h = f2bf(val);
                    k_hi[rowoff + (col - 64)] = h;
                    k_lo[rowoff + (col - 64)] = f2bf_trunc(val - bf2f(h));
                } else {
                    v_t[((size_t)b * 64 + (col - 128)) * SEQ + s] = f2bf(val);
                }
            }
        }
    }
}

// ---------------------------------------------------------------------------
// Kernel 2: causal flash attention (unchanged from R14: 32x32x16, 3-buffer
// 2-ahead counted-vmcnt DMA pipeline, permlane pack, setprio, Z=8, bf16
// partials).
// ---------------------------------------------------------------------------
__global__ __launch_bounds__(256)
void attn_kernel(const ushort* __restrict__ q_hi, const ushort* __restrict__ q_lo,
                 const ushort* __restrict__ k_hi, const ushort* __restrict__ k_lo,
                 const ushort* __restrict__ v_t,
                 ushort* __restrict__ oP, float* __restrict__ mP,
                 float* __restrict__ lP, int Z)
{
    __shared__ __align__(16) ushort kv[3][3][64][64];   // [buf][Khi|Klo|V][row][col]

    const int t    = threadIdx.x;
    const int lane = t & 63;
    const int w    = t >> 6;
    const int l31  = lane & 31;
    const int h8   = (lane >> 5) << 3;
    const int sw   = (lane & 7) << 3;
    const int b    = blockIdx.x & 7;
    const int pr   = (blockIdx.x >> 3) & 7;
    const int z    = blockIdx.x >> 6;
    const int qA   = 15 - pr;
    const int qB   = pr;
    const int cA   = 2 * qA + 2;
    const int T    = 34;

    const ushort* qhb = q_hi + (size_t)b * SEQ * 64;
    const ushort* qlb = q_lo + (size_t)b * SEQ * 64;
    const ushort* khb = k_hi + (size_t)b * SEQ * 64;
    const ushort* klb = k_lo + (size_t)b * SEQ * 64;
    const ushort* vtb = v_t + (size_t)b * 64 * SEQ;
    ushort* oPz = oP + (size_t)z * 1048576u;
    float*  mPz = mP + (size_t)z * 16384u;
    float*  lPz = lP + (size_t)z * 16384u;

    const int srow8 = lane >> 3;
    const int scol  = ((lane & 7) << 3) ^ ((lane >> 3) << 3);

    auto stage = [&](int g, int cbuf) {
        const int kk = (g < cA) ? g : g - cA;
        const int j0 = kk << 6;
        ushort* base = &kv[cbuf][0][0][0];
#pragma unroll
        for (int s = 0; s < 6; ++s) {
            const int i = w * 6 + s;
            const int row = ((i & 7) << 3) + srow8;
            const ushort* gp;
            if (i < 8)       gp = khb + (size_t)(j0 + row) * 64 + scol;
            else if (i < 16) gp = klb + (size_t)(j0 + row) * 64 + scol;
            else             gp = vtb + (size_t)row * SEQ + j0 + scol;
            __builtin_amdgcn_global_load_lds(
                (const __attribute__((address_space(1))) void*)gp,
                (__attribute__((address_space(3))) void*)(base + i * 512),
                16, 0, 0);
        }
    };

    auto loadQ = [&](int qb, short8 (&qh)[4], short8 (&ql)[4]) {
#pragma unroll
        for (int ks = 0; ks < 4; ++ks) {
            size_t off = (size_t)(qb * 128 + w * 32 + l31) * 64 + ks * 16 + h8;
            qh[ks] = *(const short8*)(qhb + off);
            ql[ks] = *(const short8*)(qlb + off);
        }
    };

    auto body = [&](int kk, int qb, f32x16 (&o)[2], float& m_run, float& l_run,
                    short8 (&qh)[4], short8 (&ql)[4], int cbuf) {
        const ushort* K0 = &kv[cbuf][0][0][0];
        const ushort* K1 = &kv[cbuf][1][0][0];
        const ushort* VT = &kv[cbuf][2][0][0];

        f32x16 sacc[2];
#pragma unroll
        for (int i = 0; i < 16; ++i) { sacc[0][i] = 0.f; sacc[1][i] = 0.f; }
        __builtin_amdgcn_s_setprio(1);
#pragma unroll
        for (int kt = 0; kt < 2; ++kt) {
            const int rb = (kt * 32 + l31) * 64;
#pragma unroll
            for (int ks = 0; ks < 4; ++ks) {
                const int c = (ks * 16 + h8) ^ sw;
                short8 ah = *(const short8*)(K0 + rb + c);
                short8 al = *(const short8*)(K1 + rb + c);
                sacc[kt] = __builtin_amdgcn_mfma_f32_32x32x16_bf16(ah, qh[ks], sacc[kt], 0, 0, 0);
                sacc[kt] = __builtin_amdgcn_mfma_f32_32x32x16_bf16(ah, ql[ks], sacc[kt], 0, 0, 0);
                sacc[kt] = __builtin_amdgcn_mfma_f32_32x32x16_bf16(al, qh[ks], sacc[kt], 0, 0, 0);
            }
        }
        __builtin_amdgcn_s_setprio(0);

        if ((kk >> 1) == qb) {
            const int q   = qb * 128 + w * 32 + l31;
            const int hi4 = (lane >> 5) << 2;
#pragma unroll
            for (int kt = 0; kt < 2; ++kt) {
                const int kb = kk * 64 + kt * 32 + hi4;
#pragma unroll
                for (int reg = 0; reg < 16; ++reg) {
                    const int key = kb + (reg & 3) + 8 * (reg >> 2);
                    if (key > q) sacc[kt][reg] = -1e30f;
                }
            }
        }

        float t8[8];
#pragma unroll
        for (int j = 0; j < 8; ++j)
            t8[j] = fmaxf(fmaxf(sacc[0][2*j], sacc[0][2*j+1]),
                          fmaxf(sacc[1][2*j], sacc[1][2*j+1]));
        float mx = fmaxf(fmaxf(fmaxf(t8[0], t8[1]), fmaxf(t8[2], t8[3])),
                         fmaxf(fmaxf(t8[4], t8[5]), fmaxf(t8[6], t8[7])));
        mx = fmaxf(mx, __shfl_xor(mx, 32));
        float mn   = fmaxf(m_run, mx);
        float corr = exp2f(m_run - mn);
        float p[2][16];
        float lt = 0.f;
#pragma unroll
        for (int kt = 0; kt < 2; ++kt)
#pragma unroll
            for (int reg = 0; reg < 16; ++reg) {
                p[kt][reg] = exp2f(sacc[kt][reg] - mn);
                lt += p[kt][reg];
            }
        lt += __shfl_xor(lt, 32);
        m_run = mn;
        l_run = l_run * corr + lt;
        o[0] = o[0] * corr;
        o[1] = o[1] * corr;

#pragma unroll
        for (int kt = 0; kt < 2; ++kt) {
            uint pk[8];
#pragma unroll
            for (int j = 0; j < 8; ++j) pk[j] = cvtpk(p[kt][2*j], p[kt][2*j+1]);
            U8 f0, f1;
#if __has_builtin(__builtin_amdgcn_permlane32_swap)
            uint2v a0 = __builtin_amdgcn_permlane32_swap(pk[0], pk[2], false, false);
            uint2v b0 = __builtin_amdgcn_permlane32_swap(pk[1], pk[3], false, false);
            uint2v a1 = __builtin_amdgcn_permlane32_swap(pk[4], pk[6], false, false);
            uint2v b1 = __builtin_amdgcn_permlane32_swap(pk[5], pk[7], false, false);
            f0.u[0] = a0.x; f0.u[1] = b0.x; f0.u[2] = a0.y; f0.u[3] = b0.y;
            f1.u[0] = a1.x; f1.u[1] = b1.x; f1.u[2] = a1.y; f1.u[3] = b1.y;
#else
            const bool hiH = (lane >= 32);
            uint rx[8];
#pragma unroll
            for (int j = 0; j < 8; ++j) rx[j] = (uint)__shfl_xor((int)pk[j], 32);
            f0.u[0] = hiH ? rx[2] : pk[0];
            f0.u[1] = hiH ? rx[3] : pk[1];
            f0.u[2] = hiH ? pk[2] : rx[0];
            f0.u[3] = hiH ? pk[3] : rx[1];
            f1.u[0] = hiH ? rx[6] : pk[4];
            f1.u[1] = hiH ? rx[7] : pk[5];
            f1.u[2] = hiH ? pk[6] : rx[4];
            f1.u[3] = hiH ? pk[7] : rx[5];
#endif
            __builtin_amdgcn_s_setprio(1);
#pragma unroll
            for (int ht = 0; ht < 2; ++ht) {
                const int row = ht * 32 + l31;
#pragma unroll
                for (int s2 = 0; s2 < 2; ++s2) {
                    const int c = (kt * 32 + s2 * 16 + h8) ^ sw;
                    short8 av = *(const short8*)(VT + row * 64 + c);
                    o[ht] = __builtin_amdgcn_mfma_f32_32x32x16_bf16(
                                av, (s2 ? f1.s : f0.s), o[ht], 0, 0, 0);
                }
            }
            __builtin_amdgcn_s_setprio(0);
        }
    };

    auto storeP = [&](int qb, f32x16 (&o)[2], float m_run, float l_run) {
        const size_t rowq = (size_t)b * SEQ + qb * 128 + w * 32 + l31;
        const int hb = (lane >> 5) << 2;
        ushort* op = oPz + rowq * 64;
#pragma unroll
        for (int ht = 0; ht < 2; ++ht)
#pragma unroll
            for (int rq = 0; rq < 4; ++rq) {
                uint u0 = cvtpk(o[ht][4*rq],     o[ht][4*rq + 1]);
                uint u1 = cvtpk(o[ht][4*rq + 2], o[ht][4*rq + 3]);
                *(uint*)(op + ht * 32 + rq * 8 + hb)     = u0;
                *(uint*)(op + ht * 32 + rq * 8 + hb + 2) = u1;
            }
        if (lane < 32) { mPz[rowq] = m_run; lPz[rowq] = l_run; }
    };

    short8 qh[4], ql[4];
    f32x16 o[2];
    float m_run, l_run;

    const int cnt = (T - 1 - z) / Z + 1;
    stage(z, 0);
    stage(z + Z, 1);
    loadQ(qA, qh, ql);
#pragma unroll
    for (int i = 0; i < 16; ++i) { o[0][i] = 0.f; o[1][i] = 0.f; }
    m_run = -INFINITY; l_run = 0.f;
    bool inB = false;

    for (int i = 0; i < cnt; ++i) {
        const int g = z + i * Z;
        if (i + 1 < cnt) asm volatile("s_waitcnt vmcnt(6)" ::: "memory");
        else             asm volatile("s_waitcnt vmcnt(0)" ::: "memory");
        __builtin_amdgcn_s_barrier();
        if (i + 2 < cnt) stage(z + (i + 2) * Z, (i + 2) % 3);
        if (g >= cA && !inB) {
            storeP(qA, o, m_run, l_run);
            loadQ(qB, qh, ql);
#pragma unroll
            for (int j = 0; j < 16; ++j) { o[0][j] = 0.f; o[1][j] = 0.f; }
            m_run = -INFINITY; l_run = 0.f;
            inB = true;
        }
        body(g < cA ? g : g - cA, g < cA ? qA : qB, o, m_run, l_run, qh, ql, i % 3);
    }

    if (!inB) {
        storeP(qA, o, m_run, l_run);
        // this slice never reached qB: store neutral partials
        const size_t rowq = (size_t)b * SEQ + qB * 128 + w * 32 + l31;
        ushort* op = oPz + rowq * 64;
        const int hb = (lane >> 5) << 2;
#pragma unroll
        for (int ht = 0; ht < 2; ++ht)
#pragma unroll
            for (int rq = 0; rq < 4; ++rq) {
                *(uint*)(op + ht * 32 + rq * 8 + hb)     = 0u;
                *(uint*)(op + ht * 32 + rq * 8 + hb + 2) = 0u;
            }
        if (lane < 32) { mPz[rowq] = -INFINITY; lPz[rowq] = 0.f; }
    } else {
        storeP(qB, o, m_run, l_run);
    }
}

// ---------------------------------------------------------------------------
// Kernel 3: merge Z k-slice partials (bf16 oP).
// ---------------------------------------------------------------------------
__global__ __launch_bounds__(256)
void merge_kernel(const ushort* __restrict__ oP, const float* __restrict__ mP,
                  const float* __restrict__ lP, float* __restrict__ out, int Z)
{
    int idx = blockIdx.x * 256 + threadIdx.x;   // 0..262143
    int R  = idx >> 4;
    int h0 = (idx & 15) << 2;
    float M = -INFINITY;
    for (int zz = 0; zz < Z; ++zz) M = fmaxf(M, mP[zz * 16384 + R]);
    float L = 0.f;
    float4 acc = make_float4(0.f, 0.f, 0.f, 0.f);
    for (int zz = 0; zz < Z; ++zz) {
        float c = exp2f(mP[zz * 16384 + R] - M);
        L += lP[zz * 16384 + R] * c;
        const ushort* op = oP + (size_t)zz * 1048576u + (size_t)R * 64 + h0;
        uint u0 = *(const uint*)op;
        uint u1 = *(const uint*)(op + 2);
        acc.x += bf2f((ushort)(u0 & 0xFFFFu)) * c;
        acc.y += bf2f((ushort)(u0 >> 16))     * c;
        acc.z += bf2f((ushort)(u1 & 0xFFFFu)) * c;
        acc.w += bf2f((ushort)(u1 >> 16))     * c;
    }
    float inv = 1.0f / L;
    float4 r = make_float4(acc.x * inv, acc.y * inv, acc.z * inv, acc.w * inv);
    *(float4*)(out + (size_t)R * 64 + h0) = r;
}

// ---------------------------------------------------------------------------
extern "C" void kernel_launch(void* const* d_in, const int* in_sizes, int n_in,
                              void* d_out, int out_size, void* d_ws, size_t ws_size,
                              hipStream_t stream)
{
    const float* x  = (const float*)d_in[0];
    const float* Wq = (const float*)d_in[1];
    const float* Wk = (const float*)d_in[2];
    const float* Wv = (const float*)d_in[3];
    float* out = (float*)d_out;

    ushort* ws = (ushort*)d_ws;
    ushort* w_hi = ws + WHI_OFF;
    ushort* w_lo = ws + WLO_OFF;
    ushort* q_hi = ws + QHI_OFF;
    ushort* q_lo = ws + QLO_OFF;
    ushort* k_hi = ws + KHI_OFF;
    ushort* k_lo = ws + KLO_OFF;
    ushort* v_t  = ws + VT_OFF;

    const int Z = 8;
    ushort* oP = ws + OPU_OFF;                 // bf16 partials [Z][16384][64]
    float*  mP = (float*)(ws + MPL_OFF);       // f32 [Z][16384]
    float*  lP = mP + (size_t)Z * 16384u;

    split_w_kernel<<<dim3(576), dim3(256), 0, stream>>>(Wq, Wk, Wv, w_hi, w_lo);
    proj_kernel<<<dim3(256), dim3(512), 0, stream>>>(x, w_hi, w_lo,
                                                     q_hi, q_lo, k_hi, k_lo, v_t);
    attn_kernel<<<dim3(64 * Z), dim3(256), 0, stream>>>(q_hi, q_lo, k_hi, k_lo, v_t,
                                                        oP, mP, lP, Z);
    merge_kernel<<<dim3(1024), dim3(256), 0, stream>>>(oP, mP, lP, out, Z);
}

// Round 17
// 66.800 us; speedup vs baseline: 1.0333x; 1.0333x over previous
//
#include <hip/hip_runtime.h>
#include <math.h>

#define EMBED 768
#define SEQ   2048
#define NB    8
// sqrt(768) * log2(e): scores are produced directly in log2 domain
#define QSCALE 39.98113776623437f

typedef short  short4v __attribute__((ext_vector_type(4)));
typedef short  short8 __attribute__((ext_vector_type(8)));
typedef float  f32x4  __attribute__((ext_vector_type(4)));
typedef float  f32x16 __attribute__((ext_vector_type(16)));
typedef unsigned int uint2v __attribute__((ext_vector_type(2)));

// ws layout, ushort element offsets
#define WHI_OFF  0u
#define WLO_OFF  147456u
#define QHI_OFF  294912u
#define QLO_OFF  (294912u + 1u*1048576u)
#define KHI_OFF  (294912u + 2u*1048576u)
#define KLO_OFF  (294912u + 3u*1048576u)
#define VT_OFF   (294912u + 4u*1048576u)
// bf16 partial region starts right after the ushort q/k/v region
#define OPU_OFF  5537792u                   // ushort offset of oP[8][16384][64] (bf16)
#define MPL_OFF  (5537792u + 8u*1048576u)   // ushort offset where f32 m/l begin

__device__ __forceinline__ ushort f2bf(float f) {          // round-to-nearest
    unsigned u = __float_as_uint(f);
    return (ushort)((u + 0x7FFFu + ((u >> 16) & 1u)) >> 16);
}
__device__ __forceinline__ ushort f2bf_trunc(float f) {    // cheap, for lo part
    return (ushort)(__float_as_uint(f) >> 16);
}
__device__ __forceinline__ float bf2f(ushort h) {
    return __uint_as_float(((unsigned)h) << 16);
}
__device__ __forceinline__ uint cvtpk(float a, float b) {  // [bf16(a) | bf16(b)<<16]
    uint r;
    asm("v_cvt_pk_bf16_f32 %0, %1, %2" : "=v"(r) : "v"(a), "v"(b));
    return r;
}

union U8 { uint u[4]; short8 s; };

// ---------------------------------------------------------------------------
// Kernel 0: split W into bf16 hi/lo.  rows: [0,64)=Wq*QSCALE, [64,128)=Wk,
// [128,192)=Wv.
// ---------------------------------------------------------------------------
__global__ __launch_bounds__(256)
void split_w_kernel(const float* __restrict__ Wq, const float* __restrict__ Wk,
                    const float* __restrict__ Wv,
                    ushort* __restrict__ w_hi, ushort* __restrict__ w_lo)
{
    int idx = blockIdx.x * 256 + threadIdx.x;
    if (idx >= 192 * EMBED) return;
    int row = idx / EMBED, e = idx - row * EMBED;
    float f;
    if (row < 64)       f = Wq[row * EMBED + e] * QSCALE;
    else if (row < 128) f = Wk[(row - 64) * EMBED + e];
    else                f = Wv[(row - 128) * EMBED + e];
    ushort hi = f2bf(f);
    w_hi[idx] = hi;
    w_lo[idx] = f2bf_trunc(f - bf2f(hi));
}

// ---------------------------------------------------------------------------
// Kernel 1 (v9): QKV projection -- BM=32, 256 thr = 4 waves, K-chunk 32,
// LDS 61 KB double-buffered -> TWO blocks/CU co-resident (the attn-proven
// lever: partner block hides barrier/drain stalls).  R12's register pipeline
// re-parameterized: 3 named register sets (6 loads each), counted
// s_waitcnt vmcnt(12/6/0), one s_barrier per chunk, 24 unrolled chunks.
// Wave w: all 32 rows x n-tiles {w, 4+w, 8+w} = 1 q + 1 k + 1 v tile
// (14 MFMA vs 9 b128 LDS reads per chunk).  Padded [40] rows (80B stride,
// 16B-aligned, bank-traced conflict-free).
// ---------------------------------------------------------------------------
__global__ __launch_bounds__(256)
void proj_kernel(const float* __restrict__ x,
                 const ushort* __restrict__ w_hi, const ushort* __restrict__ w_lo,
                 ushort* __restrict__ q_hi, ushort* __restrict__ q_lo,
                 ushort* __restrict__ k_hi, ushort* __restrict__ k_lo,
                 ushort* __restrict__ v_t)
{
    __shared__ __align__(16) ushort xah[2][32][40], xal[2][32][40];
    __shared__ __align__(16) ushort wbh[2][192][40];
    __shared__ __align__(16) ushort wbl[2][128][40];

    const int t    = threadIdx.x;
    const int lane = t & 63;
    const int w    = t >> 6;       // wave 0..3 -> n-tiles {w, 4+w, 8+w}
    const int ln   = lane & 15;
    const int kg   = lane >> 4;    // 0..3
    const int row0 = blockIdx.x * 32;

    // 6 global loads per thread per chunk:
    //   x:   float4 (row t>>3 of 32, 4 floats at (t&7)*4)
    //   Whi: short8 x3 (row t>>2 of 64-row thirds, 8 elems at (t&3)*8)
    //   Wlo: short8 x2
#define LOADSET(e0, XR, WH0, WH1, WH2, WL0, WL1) do {                             \
        const float* xp_ = x + (size_t)(row0 + (t >> 3)) * EMBED + (e0) + (t & 7) * 4; \
        XR = *(const float4*)xp_;                                                 \
        const ushort* wp_ = w_hi + (size_t)(t >> 2) * EMBED + (e0) + (t & 3) * 8; \
        WH0 = *(const short8*)wp_;                                                \
        WH1 = *(const short8*)(wp_ + 64 * EMBED);                                 \
        WH2 = *(const short8*)(wp_ + 128 * EMBED);                                \
        const ushort* lp_ = w_lo + (size_t)(t >> 2) * EMBED + (e0) + (t & 3) * 8; \
        WL0 = *(const short8*)lp_;                                                \
        WL1 = *(const short8*)(lp_ + 64 * EMBED);                                 \
    } while (0)

#define STORESET(BUF, XR, WH0, WH1, WH2, WL0, WL1) do {                           \
        const int xr_ = t >> 3, xc_ = (t & 7) * 4;                                \
        const float fv_[4] = {XR.x, XR.y, XR.z, XR.w};                            \
        short4v h_, l_;                                                           \
        _Pragma("unroll")                                                         \
        for (int i_ = 0; i_ < 4; ++i_) {                                          \
            ushort hh_ = f2bf(fv_[i_]);                                           \
            h_[i_] = (short)hh_;                                                  \
            l_[i_] = (short)f2bf_trunc(fv_[i_] - bf2f(hh_));                      \
        }                                                                         \
        *(short4v*)&xah[BUF][xr_][xc_] = h_;                                      \
        *(short4v*)&xal[BUF][xr_][xc_] = l_;                                      \
        const int wr_ = t >> 2, wc_ = (t & 3) * 8;                                \
        *(short8*)&wbh[BUF][wr_][wc_]       = WH0;                                \
        *(short8*)&wbh[BUF][wr_ + 64][wc_]  = WH1;                                \
        *(short8*)&wbh[BUF][wr_ + 128][wc_] = WH2;                                \
        *(short8*)&wbl[BUF][wr_][wc_]       = WL0;                                \
        *(short8*)&wbl[BUF][wr_ + 64][wc_]  = WL1;                                \
    } while (0)

#define COMPUTE(BUF) do {                                                         \
        short8 ah_[2], al_[2];                                                    \
        _Pragma("unroll")                                                         \
        for (int mt_ = 0; mt_ < 2; ++mt_) {                                       \
            ah_[mt_] = *(const short8*)&xah[BUF][mt_ * 16 + ln][kg * 8];          \
            al_[mt_] = *(const short8*)&xal[BUF][mt_ * 16 + ln][kg * 8];          \
        }                                                                         \
        __builtin_amdgcn_s_setprio(1);                                            \
        _Pragma("unroll")                                                         \
        for (int j_ = 0; j_ < 3; ++j_) {                                          \
            const int ntg_ = j_ * 4 + w;                                          \
            short8 bh_ = *(const short8*)&wbh[BUF][ntg_ * 16 + ln][kg * 8];       \
            _Pragma("unroll")                                                     \
            for (int mt_ = 0; mt_ < 2; ++mt_)                                     \
                acc[mt_][j_] = __builtin_amdgcn_mfma_f32_16x16x32_bf16(ah_[mt_], bh_, acc[mt_][j_], 0, 0, 0); \
            if (j_ < 2) {                                                         \
                short8 bl_ = *(const short8*)&wbl[BUF][ntg_ * 16 + ln][kg * 8];   \
                _Pragma("unroll")                                                 \
                for (int mt_ = 0; mt_ < 2; ++mt_) {                               \
                    acc[mt_][j_] = __builtin_amdgcn_mfma_f32_16x16x32_bf16(ah_[mt_], bl_, acc[mt_][j_], 0, 0, 0); \
                    acc[mt_][j_] = __builtin_amdgcn_mfma_f32_16x16x32_bf16(al_[mt_], bh_, acc[mt_][j_], 0, 0, 0); \
                }                                                                 \
            }                                                                     \
        }                                                                         \
        __builtin_amdgcn_s_setprio(0);                                            \
    } while (0)

    const f32x4 vzero = {0.f, 0.f, 0.f, 0.f};
    f32x4 acc[2][3];
#pragma unroll
    for (int mt = 0; mt < 2; ++mt)
#pragma unroll
        for (int j = 0; j < 3; ++j) acc[mt][j] = vzero;

    float4 xA; short8 hA0, hA1, hA2, lA0, lA1;
    float4 xB; short8 hB0, hB1, hB2, lB0, lB1;
    float4 xC; short8 hC0, hC1, hC2, lC0, lC1;

    LOADSET(0,  xA, hA0, hA1, hA2, lA0, lA1);
    LOADSET(32, xB, hB0, hB1, hB2, lB0, lB1);
    LOADSET(64, xC, hC0, hC1, hC2, lC0, lC1);

    // iter c: wait oldest set (counted), stage -> LDS buf c&1, barrier,
    // reload same set for chunk c+3, compute.  24 static instantiations.
#define ITER(C_, VMC, XR, W0, W1, W2, L0, L1) do {                                \
        asm volatile("s_waitcnt vmcnt(" #VMC ")" ::: "memory");                   \
        STORESET((C_) & 1, XR, W0, W1, W2, L0, L1);                               \
        asm volatile("s_waitcnt lgkmcnt(0)" ::: "memory");                        \
        __builtin_amdgcn_s_barrier();                                             \
        if ((C_) + 3 < 24) LOADSET(((C_) + 3) * 32, XR, W0, W1, W2, L0, L1);      \
        COMPUTE((C_) & 1);                                                        \
    } while (0)

    ITER(0,  12, xA, hA0, hA1, hA2, lA0, lA1);
    ITER(1,  12, xB, hB0, hB1, hB2, lB0, lB1);
    ITER(2,  12, xC, hC0, hC1, hC2, lC0, lC1);
    ITER(3,  12, xA, hA0, hA1, hA2, lA0, lA1);
    ITER(4,  12, xB, hB0, hB1, hB2, lB0, lB1);
    ITER(5,  12, xC, hC0, hC1, hC2, lC0, lC1);
    ITER(6,  12, xA, hA0, hA1, hA2, lA0, lA1);
    ITER(7,  12, xB, hB0, hB1, hB2, lB0, lB1);
    ITER(8,  12, xC, hC0, hC1, hC2, lC0, lC1);
    ITER(9,  12, xA, hA0, hA1, hA2, lA0, lA1);
    ITER(10, 12, xB, hB0, hB1, hB2, lB0, lB1);
    ITER(11, 12, xC, hC0, hC1, hC2, lC0, lC1);
    ITER(12, 12, xA, hA0, hA1, hA2, lA0, lA1);
    ITER(13, 12, xB, hB0, hB1, hB2, lB0, lB1);
    ITER(14, 12, xC, hC0, hC1, hC2, lC0, lC1);
    ITER(15, 12, xA, hA0, hA1, hA2, lA0, lA1);
    ITER(16, 12, xB, hB0, hB1, hB2, lB0, lB1);
    ITER(17, 12, xC, hC0, hC1, hC2, lC0, lC1);
    ITER(18, 12, xA, hA0, hA1, hA2, lA0, lA1);
    ITER(19, 12, xB, hB0, hB1, hB2, lB0, lB1);
    ITER(20, 12, xC, hC0, hC1, hC2, lC0, lC1);
    ITER(21, 12, xA, hA0, hA1, hA2, lA0, lA1);
    ITER(22,  6, xB, hB0, hB1, hB2, lB0, lB1);
    ITER(23,  0, xC, hC0, hC1, hC2, lC0, lC1);
#undef ITER
#undef LOADSET
#undef STORESET
#undef COMPUTE

    // ---- epilogue: C layout col=lane&15, row=(lane>>4)*4+reg ----
#pragma unroll
    for (int mt = 0; mt < 2; ++mt) {
        const int rbase = row0 + mt * 16 + kg * 4;
#pragma unroll
        for (int j = 0; j < 3; ++j) {
            const int col = (j * 4 + w) * 16 + ln;
#pragma unroll
            for (int r = 0; r < 4; ++r) {
                int rg = rbase + r;
                int b = rg >> 11, s = rg & 2047;
                size_t rowoff = ((size_t)b * SEQ + s) * 64;
                float val = acc[mt][j][r];
                if (col < 64) {
                    ushort h = f2bf(val);
                    q_hi[rowoff + col] = h;
                    q_lo[rowoff + col] = f2bf_trunc(val - bf2f(h));
                } else if (col < 128) {
                    ushort h = f2bf(val);
                    k_hi[rowoff + (col - 64)] = h;
                    k_lo[rowoff + (col - 64)] = f2bf_trunc(val - bf2f(h));
                } else {
                    v_t[((size_t)b * 64 + (col - 128)) * SEQ + s] = f2bf(val);
                }
            }
        }
    }
}

// ---------------------------------------------------------------------------
// Kernel 2: causal flash attention (unchanged from R14: 32x32x16, 3-buffer
// 2-ahead counted-vmcnt DMA pipeline, permlane pack, setprio, Z=8, bf16
// partials).
// ---------------------------------------------------------------------------
__global__ __launch_bounds__(256)
void attn_kernel(const ushort* __restrict__ q_hi, const ushort* __restrict__ q_lo,
                 const ushort* __restrict__ k_hi, const ushort* __restrict__ k_lo,
                 const ushort* __restrict__ v_t,
                 ushort* __restrict__ oP, float* __restrict__ mP,
                 float* __restrict__ lP, int Z)
{
    __shared__ __align__(16) ushort kv[3][3][64][64];   // [buf][Khi|Klo|V][row][col]

    const int t    = threadIdx.x;
    const int lane = t & 63;
    const int w    = t >> 6;
    const int l31  = lane & 31;
    const int h8   = (lane >> 5) << 3;
    const int sw   = (lane & 7) << 3;
    const int b    = blockIdx.x & 7;
    const int pr   = (blockIdx.x >> 3) & 7;
    const int z    = blockIdx.x >> 6;
    const int qA   = 15 - pr;
    const int qB   = pr;
    const int cA   = 2 * qA + 2;
    const int T    = 34;

    const ushort* qhb = q_hi + (size_t)b * SEQ * 64;
    const ushort* qlb = q_lo + (size_t)b * SEQ * 64;
    const ushort* khb = k_hi + (size_t)b * SEQ * 64;
    const ushort* klb = k_lo + (size_t)b * SEQ * 64;
    const ushort* vtb = v_t + (size_t)b * 64 * SEQ;
    ushort* oPz = oP + (size_t)z * 1048576u;
    float*  mPz = mP + (size_t)z * 16384u;
    float*  lPz = lP + (size_t)z * 16384u;

    const int srow8 = lane >> 3;
    const int scol  = ((lane & 7) << 3) ^ ((lane >> 3) << 3);

    auto stage = [&](int g, int cbuf) {
        const int kk = (g < cA) ? g : g - cA;
        const int j0 = kk << 6;
        ushort* base = &kv[cbuf][0][0][0];
#pragma unroll
        for (int s = 0; s < 6; ++s) {
            const int i = w * 6 + s;
            const int row = ((i & 7) << 3) + srow8;
            const ushort* gp;
            if (i < 8)       gp = khb + (size_t)(j0 + row) * 64 + scol;
            else if (i < 16) gp = klb + (size_t)(j0 + row) * 64 + scol;
            else             gp = vtb + (size_t)row * SEQ + j0 + scol;
            __builtin_amdgcn_global_load_lds(
                (const __attribute__((address_space(1))) void*)gp,
                (__attribute__((address_space(3))) void*)(base + i * 512),
                16, 0, 0);
        }
    };

    auto loadQ = [&](int qb, short8 (&qh)[4], short8 (&ql)[4]) {
#pragma unroll
        for (int ks = 0; ks < 4; ++ks) {
            size_t off = (size_t)(qb * 128 + w * 32 + l31) * 64 + ks * 16 + h8;
            qh[ks] = *(const short8*)(qhb + off);
            ql[ks] = *(const short8*)(qlb + off);
        }
    };

    auto body = [&](int kk, int qb, f32x16 (&o)[2], float& m_run, float& l_run,
                    short8 (&qh)[4], short8 (&ql)[4], int cbuf) {
        const ushort* K0 = &kv[cbuf][0][0][0];
        const ushort* K1 = &kv[cbuf][1][0][0];
        const ushort* VT = &kv[cbuf][2][0][0];

        f32x16 sacc[2];
#pragma unroll
        for (int i = 0; i < 16; ++i) { sacc[0][i] = 0.f; sacc[1][i] = 0.f; }
        __builtin_amdgcn_s_setprio(1);
#pragma unroll
        for (int kt = 0; kt < 2; ++kt) {
            const int rb = (kt * 32 + l31) * 64;
#pragma unroll
            for (int ks = 0; ks < 4; ++ks) {
                const int c = (ks * 16 + h8) ^ sw;
                short8 ah = *(const short8*)(K0 + rb + c);
                short8 al = *(const short8*)(K1 + rb + c);
                sacc[kt] = __builtin_amdgcn_mfma_f32_32x32x16_bf16(ah, qh[ks], sacc[kt], 0, 0, 0);
                sacc[kt] = __builtin_amdgcn_mfma_f32_32x32x16_bf16(ah, ql[ks], sacc[kt], 0, 0, 0);
                sacc[kt] = __builtin_amdgcn_mfma_f32_32x32x16_bf16(al, qh[ks], sacc[kt], 0, 0, 0);
            }
        }
        __builtin_amdgcn_s_setprio(0);

        if ((kk >> 1) == qb) {
            const int q   = qb * 128 + w * 32 + l31;
            const int hi4 = (lane >> 5) << 2;
#pragma unroll
            for (int kt = 0; kt < 2; ++kt) {
                const int kb = kk * 64 + kt * 32 + hi4;
#pragma unroll
                for (int reg = 0; reg < 16; ++reg) {
                    const int key = kb + (reg & 3) + 8 * (reg >> 2);
                    if (key > q) sacc[kt][reg] = -1e30f;
                }
            }
        }

        float t8[8];
#pragma unroll
        for (int j = 0; j < 8; ++j)
            t8[j] = fmaxf(fmaxf(sacc[0][2*j], sacc[0][2*j+1]),
                          fmaxf(sacc[1][2*j], sacc[1][2*j+1]));
        float mx = fmaxf(fmaxf(fmaxf(t8[0], t8[1]), fmaxf(t8[2], t8[3])),
                         fmaxf(fmaxf(t8[4], t8[5]), fmaxf(t8[6], t8[7])));
        mx = fmaxf(mx, __shfl_xor(mx, 32));
        float mn   = fmaxf(m_run, mx);
        float corr = exp2f(m_run - mn);
        float p[2][16];
        float lt = 0.f;
#pragma unroll
        for (int kt = 0; kt < 2; ++kt)
#pragma unroll
            for (int reg = 0; reg < 16; ++reg) {
                p[kt][reg] = exp2f(sacc[kt][reg] - mn);
                lt += p[kt][reg];
            }
        lt += __shfl_xor(lt, 32);
        m_run = mn;
        l_run = l_run * corr + lt;
        o[0] = o[0] * corr;
        o[1] = o[1] * corr;

#pragma unroll
        for (int kt = 0; kt < 2; ++kt) {
            uint pk[8];
#pragma unroll
            for (int j = 0; j < 8; ++j) pk[j] = cvtpk(p[kt][2*j], p[kt][2*j+1]);
            U8 f0, f1;
#if __has_builtin(__builtin_amdgcn_permlane32_swap)
            uint2v a0 = __builtin_amdgcn_permlane32_swap(pk[0], pk[2], false, false);
            uint2v b0 = __builtin_amdgcn_permlane32_swap(pk[1], pk[3], false, false);
            uint2v a1 = __builtin_amdgcn_permlane32_swap(pk[4], pk[6], false, false);
            uint2v b1 = __builtin_amdgcn_permlane32_swap(pk[5], pk[7], false, false);
            f0.u[0] = a0.x; f0.u[1] = b0.x; f0.u[2] = a0.y; f0.u[3] = b0.y;
            f1.u[0] = a1.x; f1.u[1] = b1.x; f1.u[2] = a1.y; f1.u[3] = b1.y;
#else
            const bool hiH = (lane >= 32);
            uint rx[8];
#pragma unroll
            for (int j = 0; j < 8; ++j) rx[j] = (uint)__shfl_xor((int)pk[j], 32);
            f0.u[0] = hiH ? rx[2] : pk[0];
            f0.u[1] = hiH ? rx[3] : pk[1];
            f0.u[2] = hiH ? pk[2] : rx[0];
            f0.u[3] = hiH ? pk[3] : rx[1];
            f1.u[0] = hiH ? rx[6] : pk[4];
            f1.u[1] = hiH ? rx[7] : pk[5];
            f1.u[2] = hiH ? pk[6] : rx[4];
            f1.u[3] = hiH ? pk[7] : rx[5];
#endif
            __builtin_amdgcn_s_setprio(1);
#pragma unroll
            for (int ht = 0; ht < 2; ++ht) {
                const int row = ht * 32 + l31;
#pragma unroll
                for (int s2 = 0; s2 < 2; ++s2) {
                    const int c = (kt * 32 + s2 * 16 + h8) ^ sw;
                    short8 av = *(const short8*)(VT + row * 64 + c);
                    o[ht] = __builtin_amdgcn_mfma_f32_32x32x16_bf16(
                                av, (s2 ? f1.s : f0.s), o[ht], 0, 0, 0);
                }
            }
            __builtin_amdgcn_s_setprio(0);
        }
    };

    auto storeP = [&](int qb, f32x16 (&o)[2], float m_run, float l_run) {
        const size_t rowq = (size_t)b * SEQ + qb * 128 + w * 32 + l31;
        const int hb = (lane >> 5) << 2;
        ushort* op = oPz + rowq * 64;
#pragma unroll
        for (int ht = 0; ht < 2; ++ht)
#pragma unroll
            for (int rq = 0; rq < 4; ++rq) {
                uint u0 = cvtpk(o[ht][4*rq],     o[ht][4*rq + 1]);
                uint u1 = cvtpk(o[ht][4*rq + 2], o[ht][4*rq + 3]);
                *(uint*)(op + ht * 32 + rq * 8 + hb)     = u0;
                *(uint*)(op + ht * 32 + rq * 8 + hb + 2) = u1;
            }
        if (lane < 32) { mPz[rowq] = m_run; lPz[rowq] = l_run; }
    };

    short8 qh[4], ql[4];
    f32x16 o[2];
    float m_run, l_run;

    const int cnt = (T - 1 - z) / Z + 1;
    stage(z, 0);
    stage(z + Z, 1);
    loadQ(qA, qh, ql);
#pragma unroll
    for (int i = 0; i < 16; ++i) { o[0][i] = 0.f; o[1][i] = 0.f; }
    m_run = -INFINITY; l_run = 0.f;
    bool inB = false;

    for (int i = 0; i < cnt; ++i) {
        const int g = z + i * Z;
        if (i + 1 < cnt) asm volatile("s_waitcnt vmcnt(6)" ::: "memory");
        else             asm volatile("s_waitcnt vmcnt(0)" ::: "memory");
        __builtin_amdgcn_s_barrier();
        if (i + 2 < cnt) stage(z + (i + 2) * Z, (i + 2) % 3);
        if (g >= cA && !inB) {
            storeP(qA, o, m_run, l_run);
            loadQ(qB, qh, ql);
#pragma unroll
            for (int j = 0; j < 16; ++j) { o[0][j] = 0.f; o[1][j] = 0.f; }
            m_run = -INFINITY; l_run = 0.f;
            inB = true;
        }
        body(g < cA ? g : g - cA, g < cA ? qA : qB, o, m_run, l_run, qh, ql, i % 3);
    }

    if (!inB) {
        storeP(qA, o, m_run, l_run);
        // this slice never reached qB: store neutral partials
        const size_t rowq = (size_t)b * SEQ + qB * 128 + w * 32 + l31;
        ushort* op = oPz + rowq * 64;
        const int hb = (lane >> 5) << 2;
#pragma unroll
        for (int ht = 0; ht < 2; ++ht)
#pragma unroll
            for (int rq = 0; rq < 4; ++rq) {
                *(uint*)(op + ht * 32 + rq * 8 + hb)     = 0u;
                *(uint*)(op + ht * 32 + rq * 8 + hb + 2) = 0u;
            }
        if (lane < 32) { mPz[rowq] = -INFINITY; lPz[rowq] = 0.f; }
    } else {
        storeP(qB, o, m_run, l_run);
    }
}

// ---------------------------------------------------------------------------
// Kernel 3: merge Z k-slice partials (bf16 oP).
// ---------------------------------------------------------------------------
__global__ __launch_bounds__(256)
void merge_kernel(const ushort* __restrict__ oP, const float* __restrict__ mP,
                  const float* __restrict__ lP, float* __restrict__ out, int Z)
{
    int idx = blockIdx.x * 256 + threadIdx.x;   // 0..262143
    int R  = idx >> 4;
    int h0 = (idx & 15) << 2;
    float M = -INFINITY;
    for (int zz = 0; zz < Z; ++zz) M = fmaxf(M, mP[zz * 16384 + R]);
    float L = 0.f;
    float4 acc = make_float4(0.f, 0.f, 0.f, 0.f);
    for (int zz = 0; zz < Z; ++zz) {
        float c = exp2f(mP[zz * 16384 + R] - M);
        L += lP[zz * 16384 + R] * c;
        const ushort* op = oP + (size_t)zz * 1048576u + (size_t)R * 64 + h0;
        uint u0 = *(const uint*)op;
        uint u1 = *(const uint*)(op + 2);
        acc.x += bf2f((ushort)(u0 & 0xFFFFu)) * c;
        acc.y += bf2f((ushort)(u0 >> 16))     * c;
        acc.z += bf2f((ushort)(u1 & 0xFFFFu)) * c;
        acc.w += bf2f((ushort)(u1 >> 16))     * c;
    }
    float inv = 1.0f / L;
    float4 r = make_float4(acc.x * inv, acc.y * inv, acc.z * inv, acc.w * inv);
    *(float4*)(out + (size_t)R * 64 + h0) = r;
}

// ---------------------------------------------------------------------------
extern "C" void kernel_launch(void* const* d_in, const int* in_sizes, int n_in,
                              void* d_out, int out_size, void* d_ws, size_t ws_size,
                              hipStream_t stream)
{
    const float* x  = (const float*)d_in[0];
    const float* Wq = (const float*)d_in[1];
    const float* Wk = (const float*)d_in[2];
    const float* Wv = (const float*)d_in[3];
    float* out = (float*)d_out;

    ushort* ws = (ushort*)d_ws;
    ushort* w_hi = ws + WHI_OFF;
    ushort* w_lo = ws + WLO_OFF;
    ushort* q_hi = ws + QHI_OFF;
    ushort* q_lo = ws + QLO_OFF;
    ushort* k_hi = ws + KHI_OFF;
    ushort* k_lo = ws + KLO_OFF;
    ushort* v_t  = ws + VT_OFF;

    const int Z = 8;
    ushort* oP = ws + OPU_OFF;                 // bf16 partials [Z][16384][64]
    float*  mP = (float*)(ws + MPL_OFF);       // f32 [Z][16384]
    float*  lP = mP + (size_t)Z * 16384u;

    split_w_kernel<<<dim3(576), dim3(256), 0, stream>>>(Wq, Wk, Wv, w_hi, w_lo);
    proj_kernel<<<dim3(512), dim3(256), 0, stream>>>(x, w_hi, w_lo,
                                                     q_hi, q_lo, k_hi, k_lo, v_t);
    attn_kernel<<<dim3(64 * Z), dim3(256), 0, stream>>>(q_hi, q_lo, k_hi, k_lo, v_t,
                                                        oP, mP, lP, Z);
    merge_kernel<<<dim3(1024), dim3(256), 0, stream>>>(oP, mP, lP, out, Z);
}

// Round 18
// 55.417 us; speedup vs baseline: 1.2456x; 1.2054x over previous
//
#include <hip/hip_runtime.h>
#include <math.h>

#define EMBED 768
#define SEQ   2048
#define NB    8
// sqrt(768) * log2(e): scores are produced directly in log2 domain
#define QSCALE 39.98113776623437f

typedef short  short4v __attribute__((ext_vector_type(4)));
typedef short  short8 __attribute__((ext_vector_type(8)));
typedef float  f32x4  __attribute__((ext_vector_type(4)));
typedef float  f32x16 __attribute__((ext_vector_type(16)));
typedef unsigned int uint2v __attribute__((ext_vector_type(2)));

// ws layout, ushort element offsets
#define WHI_OFF  0u
#define WLO_OFF  147456u
#define QHI_OFF  294912u
#define QLO_OFF  (294912u + 1u*1048576u)
#define KHI_OFF  (294912u + 2u*1048576u)
#define KLO_OFF  (294912u + 3u*1048576u)
#define VT_OFF   (294912u + 4u*1048576u)
// bf16 partial region starts right after the ushort q/k/v region
#define OPU_OFF  5537792u                   // ushort offset of oP[8][16384][64] (bf16)
#define MPL_OFF  (5537792u + 8u*1048576u)   // ushort offset where f32 m/l begin

__device__ __forceinline__ ushort f2bf(float f) {          // round-to-nearest
    unsigned u = __float_as_uint(f);
    return (ushort)((u + 0x7FFFu + ((u >> 16) & 1u)) >> 16);
}
__device__ __forceinline__ ushort f2bf_trunc(float f) {    // cheap, for lo part
    return (ushort)(__float_as_uint(f) >> 16);
}
__device__ __forceinline__ float bf2f(ushort h) {
    return __uint_as_float(((unsigned)h) << 16);
}
__device__ __forceinline__ uint cvtpk(float a, float b) {  // [bf16(a) | bf16(b)<<16]
    uint r;
    asm("v_cvt_pk_bf16_f32 %0, %1, %2" : "=v"(r) : "v"(a), "v"(b));
    return r;
}

union U8 { uint u[4]; short8 s; };

// ---------------------------------------------------------------------------
// Kernel 0: split W into bf16 hi/lo.  rows: [0,64)=Wq*QSCALE, [64,128)=Wk,
// [128,192)=Wv.
// ---------------------------------------------------------------------------
__global__ __launch_bounds__(256)
void split_w_kernel(const float* __restrict__ Wq, const float* __restrict__ Wk,
                    const float* __restrict__ Wv,
                    ushort* __restrict__ w_hi, ushort* __restrict__ w_lo)
{
    int idx = blockIdx.x * 256 + threadIdx.x;
    if (idx >= 192 * EMBED) return;
    int row = idx / EMBED, e = idx - row * EMBED;
    float f;
    if (row < 64)       f = Wq[row * EMBED + e] * QSCALE;
    else if (row < 128) f = Wk[(row - 64) * EMBED + e];
    else                f = Wv[(row - 128) * EMBED + e];
    ushort hi = f2bf(f);
    w_hi[idx] = hi;
    w_lo[idx] = f2bf_trunc(f - bf2f(hi));
}

// ---------------------------------------------------------------------------
// Kernel 1 (R12 = best measured, ~32us): QKV projection.
// Conflict-free padded-LDS ([72] stride) 16x16 inner loop, BM=64, 512 thr =
// 8 waves, 2 waves/SIMD, LDS double-buffer; THREE-deep register prefetch
// (A/B/C sets, 12 fully-unrolled chunks, static indices), counted
// vmcnt(14/7/0).  q/k cols 3-product split-bf16; v single product.
// ---------------------------------------------------------------------------
__global__ __launch_bounds__(512)
void proj_kernel(const float* __restrict__ x,
                 const ushort* __restrict__ w_hi, const ushort* __restrict__ w_lo,
                 ushort* __restrict__ q_hi, ushort* __restrict__ q_lo,
                 ushort* __restrict__ k_hi, ushort* __restrict__ k_lo,
                 ushort* __restrict__ v_t)
{
    __shared__ __align__(16) ushort xah[2][64][72], xal[2][64][72];
    __shared__ __align__(16) ushort wbh[2][192][72];
    __shared__ __align__(16) ushort wbl[2][128][72];

    const int t    = threadIdx.x;
    const int lane = t & 63;
    const int wid  = t >> 6;       // 0..7
    const int wm   = wid >> 2;     // 0,1: rows wm*32..+31
    const int wn   = wid & 3;      // 0..3: n-tiles {wn, 4+wn, 8+wn}
    const int ln   = lane & 15;
    const int kg   = lane >> 4;
    const int row0 = blockIdx.x * 64;

#define LOADSET(e0, XR0, XR1, WH0, WH1, WH2, WL0, WL1) do {                       \
        const float* xp_ = x + (size_t)(row0 + (t >> 4)) * EMBED + (e0) + (t & 15) * 4; \
        XR0 = *(const float4*)xp_;                                                \
        XR1 = *(const float4*)(xp_ + 32 * EMBED);                                 \
        const ushort* wp_ = w_hi + (size_t)(t >> 3) * EMBED + (e0) + (t & 7) * 8; \
        WH0 = *(const short8*)wp_;                                                \
        WH1 = *(const short8*)(wp_ + 64 * EMBED);                                 \
        WH2 = *(const short8*)(wp_ + 128 * EMBED);                                \
        const ushort* lp_ = w_lo + (size_t)(t >> 3) * EMBED + (e0) + (t & 7) * 8; \
        WL0 = *(const short8*)lp_;                                                \
        WL1 = *(const short8*)(lp_ + 64 * EMBED);                                 \
    } while (0)

#define STORESET(BUF, XR0, XR1, WH0, WH1, WH2, WL0, WL1) do {                     \
        const int xr_ = t >> 4, xc_ = (t & 15) * 4;                               \
        const float f0_[4] = {XR0.x, XR0.y, XR0.z, XR0.w};                        \
        const float f1_[4] = {XR1.x, XR1.y, XR1.z, XR1.w};                        \
        short4v h0_, l0_, h1_, l1_;                                               \
        _Pragma("unroll")                                                         \
        for (int i_ = 0; i_ < 4; ++i_) {                                          \
            ushort h_ = f2bf(f0_[i_]);                                            \
            h0_[i_] = (short)h_;                                                  \
            l0_[i_] = (short)f2bf_trunc(f0_[i_] - bf2f(h_));                      \
        }                                                                         \
        _Pragma("unroll")                                                         \
        for (int i_ = 0; i_ < 4; ++i_) {                                          \
            ushort h_ = f2bf(f1_[i_]);                                            \
            h1_[i_] = (short)h_;                                                  \
            l1_[i_] = (short)f2bf_trunc(f1_[i_] - bf2f(h_));                      \
        }                                                                         \
        *(short4v*)&xah[BUF][xr_][xc_]      = h0_;                                \
        *(short4v*)&xal[BUF][xr_][xc_]      = l0_;                                \
        *(short4v*)&xah[BUF][xr_ + 32][xc_] = h1_;                                \
        *(short4v*)&xal[BUF][xr_ + 32][xc_] = l1_;                                \
        const int wr_ = t >> 3, wc_ = (t & 7) * 8;                                \
        *(short8*)&wbh[BUF][wr_][wc_]       = WH0;                                \
        *(short8*)&wbh[BUF][wr_ + 64][wc_]  = WH1;                                \
        *(short8*)&wbh[BUF][wr_ + 128][wc_] = WH2;                                \
        *(short8*)&wbl[BUF][wr_][wc_]       = WL0;                                \
        *(short8*)&wbl[BUF][wr_ + 64][wc_]  = WL1;                                \
    } while (0)

#define COMPUTE(BUF) do {                                                         \
        short8 ah_[2][2], al_[2][2];                                              \
        _Pragma("unroll")                                                         \
        for (int mt_ = 0; mt_ < 2; ++mt_)                                         \
            _Pragma("unroll")                                                     \
            for (int ks_ = 0; ks_ < 2; ++ks_) {                                   \
                ah_[mt_][ks_] = *(const short8*)&xah[BUF][wm * 32 + mt_ * 16 + ln][ks_ * 32 + kg * 8]; \
                al_[mt_][ks_] = *(const short8*)&xal[BUF][wm * 32 + mt_ * 16 + ln][ks_ * 32 + kg * 8]; \
            }                                                                     \
        _Pragma("unroll")                                                         \
        for (int j_ = 0; j_ < 3; ++j_) {                                          \
            const int ntg_ = j_ * 4 + wn;                                         \
            _Pragma("unroll")                                                     \
            for (int ks_ = 0; ks_ < 2; ++ks_) {                                   \
                const int co_ = ks_ * 32 + kg * 8;                                \
                short8 bh_ = *(const short8*)&wbh[BUF][ntg_ * 16 + ln][co_];      \
                _Pragma("unroll")                                                 \
                for (int mt_ = 0; mt_ < 2; ++mt_)                                 \
                    acc[mt_][j_] = __builtin_amdgcn_mfma_f32_16x16x32_bf16(ah_[mt_][ks_], bh_, acc[mt_][j_], 0, 0, 0); \
                if (j_ < 2) {                                                     \
                    short8 bl_ = *(const short8*)&wbl[BUF][ntg_ * 16 + ln][co_];  \
                    _Pragma("unroll")                                             \
                    for (int mt_ = 0; mt_ < 2; ++mt_) {                           \
                        acc[mt_][j_] = __builtin_amdgcn_mfma_f32_16x16x32_bf16(ah_[mt_][ks_], bl_, acc[mt_][j_], 0, 0, 0); \
                        acc[mt_][j_] = __builtin_amdgcn_mfma_f32_16x16x32_bf16(al_[mt_][ks_], bh_, acc[mt_][j_], 0, 0, 0); \
                    }                                                             \
                }                                                                 \
            }                                                                     \
        }                                                                         \
    } while (0)

    const f32x4 vzero = {0.f, 0.f, 0.f, 0.f};
    f32x4 acc[2][3];
#pragma unroll
    for (int mt = 0; mt < 2; ++mt)
#pragma unroll
        for (int j = 0; j < 3; ++j) acc[mt][j] = vzero;

    float4 xrA0, xrA1; short8 whA0, whA1, whA2, wlA0, wlA1;
    float4 xrB0, xrB1; short8 whB0, whB1, whB2, wlB0, wlB1;
    float4 xrC0, xrC1; short8 whC0, whC1, whC2, wlC0, wlC1;

    LOADSET(0,   xrA0, xrA1, whA0, whA1, whA2, wlA0, wlA1);
    LOADSET(64,  xrB0, xrB1, whB0, whB1, whB2, wlB0, wlB1);
    LOADSET(128, xrC0, xrC1, whC0, whC1, whC2, wlC0, wlC1);

#define ITER(C_, VMC, BUF, X0, X1, W0, W1, W2, L0, L1) do {                       \
        asm volatile("s_waitcnt vmcnt(" #VMC ")" ::: "memory");                   \
        STORESET(BUF, X0, X1, W0, W1, W2, L0, L1);                                \
        asm volatile("s_waitcnt lgkmcnt(0)" ::: "memory");                        \
        __builtin_amdgcn_s_barrier();                                             \
        if ((C_) + 3 < 12) LOADSET(((C_) + 3) * 64, X0, X1, W0, W1, W2, L0, L1);  \
        COMPUTE(BUF);                                                             \
    } while (0)

    ITER(0,  14, 0, xrA0, xrA1, whA0, whA1, whA2, wlA0, wlA1);
    ITER(1,  14, 1, xrB0, xrB1, whB0, whB1, whB2, wlB0, wlB1);
    ITER(2,  14, 0, xrC0, xrC1, whC0, whC1, whC2, wlC0, wlC1);
    ITER(3,  14, 1, xrA0, xrA1, whA0, whA1, whA2, wlA0, wlA1);
    ITER(4,  14, 0, xrB0, xrB1, whB0, whB1, whB2, wlB0, wlB1);
    ITER(5,  14, 1, xrC0, xrC1, whC0, whC1, whC2, wlC0, wlC1);
    ITER(6,  14, 0, xrA0, xrA1, whA0, whA1, whA2, wlA0, wlA1);
    ITER(7,  14, 1, xrB0, xrB1, whB0, whB1, whB2, wlB0, wlB1);
    ITER(8,  14, 0, xrC0, xrC1, whC0, whC1, whC2, wlC0, wlC1);
    ITER(9,  14, 1, xrA0, xrA1, whA0, whA1, whA2, wlA0, wlA1);
    ITER(10,  7, 0, xrB0, xrB1, whB0, whB1, whB2, wlB0, wlB1);
    ITER(11,  0, 1, xrC0, xrC1, whC0, whC1, whC2, wlC0, wlC1);
#undef ITER
#undef LOADSET
#undef STORESET
#undef COMPUTE

    // ---- epilogue: C layout col=lane&15, row=(lane>>4)*4+reg ----
#pragma unroll
    for (int mt = 0; mt < 2; ++mt) {
        const int rbase = row0 + wm * 32 + mt * 16 + kg * 4;
#pragma unroll
        for (int j = 0; j < 3; ++j) {
            const int col = (j * 4 + wn) * 16 + ln;
#pragma unroll
            for (int r = 0; r < 4; ++r) {
                int rg = rbase + r;
                int b = rg >> 11, s = rg & 2047;
                size_t rowoff = ((size_t)b * SEQ + s) * 64;
                float val = acc[mt][j][r];
                if (col < 64) {
                    ushort h = f2bf(val);
                    q_hi[rowoff + col] = h;
                    q_lo[rowoff + col] = f2bf_trunc(val - bf2f(h));
                } else if (col < 128) {
                    ushort h = f2bf(val);
                    k_hi[rowoff + (col - 64)] = h;
                    k_lo[rowoff + (col - 64)] = f2bf_trunc(val - bf2f(h));
                } else {
                    v_t[((size_t)b * 64 + (col - 128)) * SEQ + s] = f2bf(val);
                }
            }
        }
    }
}

// ---------------------------------------------------------------------------
// Kernel 2: causal flash attention (R14: 32x32x16, 3-buffer 2-ahead
// counted-vmcnt DMA pipeline, permlane pack, setprio, Z=8, bf16 partials).
// ---------------------------------------------------------------------------
__global__ __launch_bounds__(256)
void attn_kernel(const ushort* __restrict__ q_hi, const ushort* __restrict__ q_lo,
                 const ushort* __restrict__ k_hi, const ushort* __restrict__ k_lo,
                 const ushort* __restrict__ v_t,
                 ushort* __restrict__ oP, float* __restrict__ mP,
                 float* __restrict__ lP, int Z)
{
    __shared__ __align__(16) ushort kv[3][3][64][64];   // [buf][Khi|Klo|V][row][col]

    const int t    = threadIdx.x;
    const int lane = t & 63;
    const int w    = t >> 6;
    const int l31  = lane & 31;
    const int h8   = (lane >> 5) << 3;
    const int sw   = (lane & 7) << 3;
    const int b    = blockIdx.x & 7;
    const int pr   = (blockIdx.x >> 3) & 7;
    const int z    = blockIdx.x >> 6;
    const int qA   = 15 - pr;
    const int qB   = pr;
    const int cA   = 2 * qA + 2;
    const int T    = 34;

    const ushort* qhb = q_hi + (size_t)b * SEQ * 64;
    const ushort* qlb = q_lo + (size_t)b * SEQ * 64;
    const ushort* khb = k_hi + (size_t)b * SEQ * 64;
    const ushort* klb = k_lo + (size_t)b * SEQ * 64;
    const ushort* vtb = v_t + (size_t)b * 64 * SEQ;
    ushort* oPz = oP + (size_t)z * 1048576u;
    float*  mPz = mP + (size_t)z * 16384u;
    float*  lPz = lP + (size_t)z * 16384u;

    const int srow8 = lane >> 3;
    const int scol  = ((lane & 7) << 3) ^ ((lane >> 3) << 3);

    auto stage = [&](int g, int cbuf) {
        const int kk = (g < cA) ? g : g - cA;
        const int j0 = kk << 6;
        ushort* base = &kv[cbuf][0][0][0];
#pragma unroll
        for (int s = 0; s < 6; ++s) {
            const int i = w * 6 + s;
            const int row = ((i & 7) << 3) + srow8;
            const ushort* gp;
            if (i < 8)       gp = khb + (size_t)(j0 + row) * 64 + scol;
            else if (i < 16) gp = klb + (size_t)(j0 + row) * 64 + scol;
            else             gp = vtb + (size_t)row * SEQ + j0 + scol;
            __builtin_amdgcn_global_load_lds(
                (const __attribute__((address_space(1))) void*)gp,
                (__attribute__((address_space(3))) void*)(base + i * 512),
                16, 0, 0);
        }
    };

    auto loadQ = [&](int qb, short8 (&qh)[4], short8 (&ql)[4]) {
#pragma unroll
        for (int ks = 0; ks < 4; ++ks) {
            size_t off = (size_t)(qb * 128 + w * 32 + l31) * 64 + ks * 16 + h8;
            qh[ks] = *(const short8*)(qhb + off);
            ql[ks] = *(const short8*)(qlb + off);
        }
    };

    auto body = [&](int kk, int qb, f32x16 (&o)[2], float& m_run, float& l_run,
                    short8 (&qh)[4], short8 (&ql)[4], int cbuf) {
        const ushort* K0 = &kv[cbuf][0][0][0];
        const ushort* K1 = &kv[cbuf][1][0][0];
        const ushort* VT = &kv[cbuf][2][0][0];

        f32x16 sacc[2];
#pragma unroll
        for (int i = 0; i < 16; ++i) { sacc[0][i] = 0.f; sacc[1][i] = 0.f; }
        __builtin_amdgcn_s_setprio(1);
#pragma unroll
        for (int kt = 0; kt < 2; ++kt) {
            const int rb = (kt * 32 + l31) * 64;
#pragma unroll
            for (int ks = 0; ks < 4; ++ks) {
                const int c = (ks * 16 + h8) ^ sw;
                short8 ah = *(const short8*)(K0 + rb + c);
                short8 al = *(const short8*)(K1 + rb + c);
                sacc[kt] = __builtin_amdgcn_mfma_f32_32x32x16_bf16(ah, qh[ks], sacc[kt], 0, 0, 0);
                sacc[kt] = __builtin_amdgcn_mfma_f32_32x32x16_bf16(ah, ql[ks], sacc[kt], 0, 0, 0);
                sacc[kt] = __builtin_amdgcn_mfma_f32_32x32x16_bf16(al, qh[ks], sacc[kt], 0, 0, 0);
            }
        }
        __builtin_amdgcn_s_setprio(0);

        if ((kk >> 1) == qb) {
            const int q   = qb * 128 + w * 32 + l31;
            const int hi4 = (lane >> 5) << 2;
#pragma unroll
            for (int kt = 0; kt < 2; ++kt) {
                const int kb = kk * 64 + kt * 32 + hi4;
#pragma unroll
                for (int reg = 0; reg < 16; ++reg) {
                    const int key = kb + (reg & 3) + 8 * (reg >> 2);
                    if (key > q) sacc[kt][reg] = -1e30f;
                }
            }
        }

        float t8[8];
#pragma unroll
        for (int j = 0; j < 8; ++j)
            t8[j] = fmaxf(fmaxf(sacc[0][2*j], sacc[0][2*j+1]),
                          fmaxf(sacc[1][2*j], sacc[1][2*j+1]));
        float mx = fmaxf(fmaxf(fmaxf(t8[0], t8[1]), fmaxf(t8[2], t8[3])),
                         fmaxf(fmaxf(t8[4], t8[5]), fmaxf(t8[6], t8[7])));
        mx = fmaxf(mx, __shfl_xor(mx, 32));
        float mn   = fmaxf(m_run, mx);
        float corr = exp2f(m_run - mn);
        float p[2][16];
        float lt = 0.f;
#pragma unroll
        for (int kt = 0; kt < 2; ++kt)
#pragma unroll
            for (int reg = 0; reg < 16; ++reg) {
                p[kt][reg] = exp2f(sacc[kt][reg] - mn);
                lt += p[kt][reg];
            }
        lt += __shfl_xor(lt, 32);
        m_run = mn;
        l_run = l_run * corr + lt;
        o[0] = o[0] * corr;
        o[1] = o[1] * corr;

#pragma unroll
        for (int kt = 0; kt < 2; ++kt) {
            uint pk[8];
#pragma unroll
            for (int j = 0; j < 8; ++j) pk[j] = cvtpk(p[kt][2*j], p[kt][2*j+1]);
            U8 f0, f1;
#if __has_builtin(__builtin_amdgcn_permlane32_swap)
            uint2v a0 = __builtin_amdgcn_permlane32_swap(pk[0], pk[2], false, false);
            uint2v b0 = __builtin_amdgcn_permlane32_swap(pk[1], pk[3], false, false);
            uint2v a1 = __builtin_amdgcn_permlane32_swap(pk[4], pk[6], false, false);
            uint2v b1 = __builtin_amdgcn_permlane32_swap(pk[5], pk[7], false, false);
            f0.u[0] = a0.x; f0.u[1] = b0.x; f0.u[2] = a0.y; f0.u[3] = b0.y;
            f1.u[0] = a1.x; f1.u[1] = b1.x; f1.u[2] = a1.y; f1.u[3] = b1.y;
#else
            const bool hiH = (lane >= 32);
            uint rx[8];
#pragma unroll
            for (int j = 0; j < 8; ++j) rx[j] = (uint)__shfl_xor((int)pk[j], 32);
            f0.u[0] = hiH ? rx[2] : pk[0];
            f0.u[1] = hiH ? rx[3] : pk[1];
            f0.u[2] = hiH ? pk[2] : rx[0];
            f0.u[3] = hiH ? pk[3] : rx[1];
            f1.u[0] = hiH ? rx[6] : pk[4];
            f1.u[1] = hiH ? rx[7] : pk[5];
            f1.u[2] = hiH ? pk[6] : rx[4];
            f1.u[3] = hiH ? pk[7] : rx[5];
#endif
            __builtin_amdgcn_s_setprio(1);
#pragma unroll
            for (int ht = 0; ht < 2; ++ht) {
                const int row = ht * 32 + l31;
#pragma unroll
                for (int s2 = 0; s2 < 2; ++s2) {
                    const int c = (kt * 32 + s2 * 16 + h8) ^ sw;
                    short8 av = *(const short8*)(VT + row * 64 + c);
                    o[ht] = __builtin_amdgcn_mfma_f32_32x32x16_bf16(
                                av, (s2 ? f1.s : f0.s), o[ht], 0, 0, 0);
                }
            }
            __builtin_amdgcn_s_setprio(0);
        }
    };

    auto storeP = [&](int qb, f32x16 (&o)[2], float m_run, float l_run) {
        const size_t rowq = (size_t)b * SEQ + qb * 128 + w * 32 + l31;
        const int hb = (lane >> 5) << 2;
        ushort* op = oPz + rowq * 64;
#pragma unroll
        for (int ht = 0; ht < 2; ++ht)
#pragma unroll
            for (int rq = 0; rq < 4; ++rq) {
                uint u0 = cvtpk(o[ht][4*rq],     o[ht][4*rq + 1]);
                uint u1 = cvtpk(o[ht][4*rq + 2], o[ht][4*rq + 3]);
                *(uint*)(op + ht * 32 + rq * 8 + hb)     = u0;
                *(uint*)(op + ht * 32 + rq * 8 + hb + 2) = u1;
            }
        if (lane < 32) { mPz[rowq] = m_run; lPz[rowq] = l_run; }
    };

    short8 qh[4], ql[4];
    f32x16 o[2];
    float m_run, l_run;

    const int cnt = (T - 1 - z) / Z + 1;
    stage(z, 0);
    stage(z + Z, 1);
    loadQ(qA, qh, ql);
#pragma unroll
    for (int i = 0; i < 16; ++i) { o[0][i] = 0.f; o[1][i] = 0.f; }
    m_run = -INFINITY; l_run = 0.f;
    bool inB = false;

    for (int i = 0; i < cnt; ++i) {
        const int g = z + i * Z;
        if (i + 1 < cnt) asm volatile("s_waitcnt vmcnt(6)" ::: "memory");
        else             asm volatile("s_waitcnt vmcnt(0)" ::: "memory");
        __builtin_amdgcn_s_barrier();
        if (i + 2 < cnt) stage(z + (i + 2) * Z, (i + 2) % 3);
        if (g >= cA && !inB) {
            storeP(qA, o, m_run, l_run);
            loadQ(qB, qh, ql);
#pragma unroll
            for (int j = 0; j < 16; ++j) { o[0][j] = 0.f; o[1][j] = 0.f; }
            m_run = -INFINITY; l_run = 0.f;
            inB = true;
        }
        body(g < cA ? g : g - cA, g < cA ? qA : qB, o, m_run, l_run, qh, ql, i % 3);
    }

    if (!inB) {
        storeP(qA, o, m_run, l_run);
        // this slice never reached qB: store neutral partials
        const size_t rowq = (size_t)b * SEQ + qB * 128 + w * 32 + l31;
        ushort* op = oPz + rowq * 64;
        const int hb = (lane >> 5) << 2;
#pragma unroll
        for (int ht = 0; ht < 2; ++ht)
#pragma unroll
            for (int rq = 0; rq < 4; ++rq) {
                *(uint*)(op + ht * 32 + rq * 8 + hb)     = 0u;
                *(uint*)(op + ht * 32 + rq * 8 + hb + 2) = 0u;
            }
        if (lane < 32) { mPz[rowq] = -INFINITY; lPz[rowq] = 0.f; }
    } else {
        storeP(qB, o, m_run, l_run);
    }
}

// ---------------------------------------------------------------------------
// Kernel 3: merge Z k-slice partials (bf16 oP).
// ---------------------------------------------------------------------------
__global__ __launch_bounds__(256)
void merge_kernel(const ushort* __restrict__ oP, const float* __restrict__ mP,
                  const float* __restrict__ lP, float* __restrict__ out, int Z)
{
    int idx = blockIdx.x * 256 + threadIdx.x;   // 0..262143
    int R  = idx >> 4;
    int h0 = (idx & 15) << 2;
    float M = -INFINITY;
    for (int zz = 0; zz < Z; ++zz) M = fmaxf(M, mP[zz * 16384 + R]);
    float L = 0.f;
    float4 acc = make_float4(0.f, 0.f, 0.f, 0.f);
    for (int zz = 0; zz < Z; ++zz) {
        float c = exp2f(mP[zz * 16384 + R] - M);
        L += lP[zz * 16384 + R] * c;
        const ushort* op = oP + (size_t)zz * 1048576u + (size_t)R * 64 + h0;
        uint u0 = *(const uint*)op;
        uint u1 = *(const uint*)(op + 2);
        acc.x += bf2f((ushort)(u0 & 0xFFFFu)) * c;
        acc.y += bf2f((ushort)(u0 >> 16))     * c;
        acc.z += bf2f((ushort)(u1 & 0xFFFFu)) * c;
        acc.w += bf2f((ushort)(u1 >> 16))     * c;
    }
    float inv = 1.0f / L;
    float4 r = make_float4(acc.x * inv, acc.y * inv, acc.z * inv, acc.w * inv);
    *(float4*)(out + (size_t)R * 64 + h0) = r;
}

// ---------------------------------------------------------------------------
extern "C" void kernel_launch(void* const* d_in, const int* in_sizes, int n_in,
                              void* d_out, int out_size, void* d_ws, size_t ws_size,
                              hipStream_t stream)
{
    const float* x  = (const float*)d_in[0];
    const float* Wq = (const float*)d_in[1];
    const float* Wk = (const float*)d_in[2];
    const float* Wv = (const float*)d_in[3];
    float* out = (float*)d_out;

    ushort* ws = (ushort*)d_ws;
    ushort* w_hi = ws + WHI_OFF;
    ushort* w_lo = ws + WLO_OFF;
    ushort* q_hi = ws + QHI_OFF;
    ushort* q_lo = ws + QLO_OFF;
    ushort* k_hi = ws + KHI_OFF;
    ushort* k_lo = ws + KLO_OFF;
    ushort* v_t  = ws + VT_OFF;

    const int Z = 8;
    ushort* oP = ws + OPU_OFF;                 // bf16 partials [Z][16384][64]
    float*  mP = (float*)(ws + MPL_OFF);       // f32 [Z][16384]
    float*  lP = mP + (size_t)Z * 16384u;

    split_w_kernel<<<dim3(576), dim3(256), 0, stream>>>(Wq, Wk, Wv, w_hi, w_lo);
    proj_kernel<<<dim3(256), dim3(512), 0, stream>>>(x, w_hi, w_lo,
                                                     q_hi, q_lo, k_hi, k_lo, v_t);
    attn_kernel<<<dim3(64 * Z), dim3(256), 0, stream>>>(q_hi, q_lo, k_hi, k_lo, v_t,
                                                        oP, mP, lP, Z);
    merge_kernel<<<dim3(1024), dim3(256), 0, stream>>>(oP, mP, lP, out, Z);
}